// Round 2
// baseline (238.506 us; speedup 1.0000x reference)
//
#include <hip/hip_runtime.h>

// LIF membrane recurrence:
//   mem[t] = mem[t-1] * 0.25 * (1 - spike[t-1]) + x[t]
//   spike[t] = (mem[t] > 0.5) ? 1 : 0
// x: (T=8, 32,128,32,32) f32; out = spikes, same shape/dtype.
// Spatial slab N = 32*128*32*32 = 4194304 elems; each thread owns 4
// contiguous elems (float4) and walks t with stride N.

#define LIF_T 8
#define LIF_N (32 * 128 * 32 * 32)      // 4194304
#define LIF_N4 (LIF_N / 4)              // 1048576 float4 columns

__global__ __launch_bounds__(256) void lif_kernel(
    const float4* __restrict__ x4, float4* __restrict__ o4) {
    const int i = blockIdx.x * 256 + threadIdx.x;   // float4 column index

    // Load all 8 timesteps up front: 8 independent global_load_dwordx4,
    // latency overlapped (addresses independent of the mem chain).
    float4 xs[LIF_T];
#pragma unroll
    for (int t = 0; t < LIF_T; ++t) {
        xs[t] = x4[(size_t)t * LIF_N4 + i];
    }

    float mx = 0.f, my = 0.f, mz = 0.f, mw = 0.f;   // membrane
    float sx = 0.f, sy = 0.f, sz = 0.f, sw = 0.f;   // spike (0/1)

#pragma unroll
    for (int t = 0; t < LIF_T; ++t) {
        // decay factor: 0.25 if no spike last step, else 0.
        // mem*d is EXACT (pow2 or zero); the single add matches numpy's
        // rounding bit-for-bit, so (mem > 0.5) can never flip vs ref.
        const float dx = (sx != 0.f) ? 0.f : 0.25f;
        const float dy = (sy != 0.f) ? 0.f : 0.25f;
        const float dz = (sz != 0.f) ? 0.f : 0.25f;
        const float dw = (sw != 0.f) ? 0.f : 0.25f;
        mx = mx * dx + xs[t].x;
        my = my * dy + xs[t].y;
        mz = mz * dz + xs[t].z;
        mw = mw * dw + xs[t].w;
        sx = (mx > 0.5f) ? 1.f : 0.f;
        sy = (my > 0.5f) ? 1.f : 0.f;
        sz = (mz > 0.5f) ? 1.f : 0.f;
        sw = (mw > 0.5f) ? 1.f : 0.f;
        float4 s;
        s.x = sx; s.y = sy; s.z = sz; s.w = sw;
        o4[(size_t)t * LIF_N4 + i] = s;
    }
}

extern "C" void kernel_launch(void* const* d_in, const int* in_sizes, int n_in,
                              void* d_out, int out_size, void* d_ws, size_t ws_size,
                              hipStream_t stream) {
    const float4* x4 = (const float4*)d_in[0];
    float4* o4 = (float4*)d_out;
    const int blocks = LIF_N4 / 256;    // 4096
    lif_kernel<<<blocks, 256, 0, stream>>>(x4, o4);
}